// Round 3
// baseline (427.591 us; speedup 1.0000x reference)
//
#include <hip/hip_runtime.h>

typedef __attribute__((ext_vector_type(8))) short short8;
typedef __attribute__((ext_vector_type(4))) float floatx4;

__device__ inline unsigned short f2bf(float f) {
  union { float f; unsigned int u; } c; c.f = f;
  unsigned int u = c.u;
  return (unsigned short)((u + 0x7fffu + ((u >> 16) & 1u)) >> 16);
}
__device__ inline float bf2f(unsigned short h) {
  union { unsigned int u; float f; } c; c.u = ((unsigned int)h) << 16;
  return c.f;
}

// ---------------- kW: fp32 -> (bf16-hi, bf16-lo) weight planes ----------------
__global__ __launch_bounds__(256) void kW(const float* __restrict__ w1,
                                          const float* __restrict__ w2,
                                          const float* __restrict__ w3,
                                          unsigned short* __restrict__ w1h,
                                          unsigned short* __restrict__ w1l,
                                          unsigned short* __restrict__ w2h,
                                          unsigned short* __restrict__ w2l,
                                          unsigned short* __restrict__ w3h,
                                          unsigned short* __restrict__ w3l) {
  int i = blockIdx.x * 256 + threadIdx.x;
  if (i < 202752) {
    float v = w1[i]; unsigned short hi = f2bf(v);
    w1h[i] = hi; w1l[i] = f2bf(v - bf2f(hi));
  } else if (i < 211968) {
    int k = i - 202752;
    float v = w2[k]; unsigned short hi = f2bf(v);
    w2h[k] = hi; w2l[k] = f2bf(v - bf2f(hi));
  } else if (i < 221184) {
    int k = i - 211968;
    float v = w3[k]; unsigned short hi = f2bf(v);
    w3h[k] = hi; w3l[k] = f2bf(v - bf2f(hi));
  }
}

// ---------------- kDesc: scrambled-unfold descriptors -> desc [12544, 2112] hi/lo bf16 ----
// tap(k1,k2) at (h',w') = x[row=(k2*56+h')/3+k1-1, col=w'+(k2*56+h')%3-1], zero-pad.
// block=(b,h',g): 3584 blocks, 320 threads. Table-driven branch-free inner loop.
__global__ __launch_bounds__(320) void kDesc(const float* __restrict__ x,
                                             unsigned short* __restrict__ descH,
                                             unsigned short* __restrict__ descL,
                                             int uselo) {
  int bid = blockIdx.x;
  int g = bid & 15;
  int h = (bid >> 4) % 56;
  int b = bid / 896;
  __shared__ float xb[144 * 58];        // [(kk*16+ch)*58 + wc], kk=k2*3+k1
  __shared__ int tOff[4][132];          // 4 LDS offsets per dl (off3 dup for 3-input)
  __shared__ int tDg[132];              // dglob per dl
  __shared__ int rowbase[9];            // gr base per kk

  int t = threadIdx.x;
  if (t < 9) {
    int k2 = t / 3, k1 = t % 3;
    rowbase[t] = (k2 * 56 + h) / 3 + k1 - 1;
  }
  if (t < 132) {
    int dl = t;
    int o0, o1, o2, o3, dg;
    if (dl < 36) {                       // x1: max over 4 sub-channels
      int a3 = dl / 9, rem = dl % 9, k1 = rem / 3, k2 = rem % 3;
      int j2k = (k2 * 56 + h) % 3;
      int base = (k2 * 3 + k1) * 16;
      o0 = (base + a3) * 58 + j2k;
      o1 = (base + 4 + a3) * 58 + j2k;
      o2 = (base + 8 + a3) * 58 + j2k;
      o3 = (base + 12 + a3) * 58 + j2k;
      dg = g * 36 + dl;
    } else if (dl < 84) {                // x2: max over k1
      int u = dl - 36, gc = u / 3, k2 = u % 3;
      int j2k = (k2 * 56 + h) % 3;
      o0 = ((k2 * 3 + 0) * 16 + gc) * 58 + j2k;
      o1 = ((k2 * 3 + 1) * 16 + gc) * 58 + j2k;
      o2 = ((k2 * 3 + 2) * 16 + gc) * 58 + j2k;
      o3 = o0;
      dg = 576 + g * 48 + u;
    } else {                             // x3: max over k2
      int u = dl - 84, gc = u / 3, k1 = u % 3;
      o0 = ((0 * 3 + k1) * 16 + gc) * 58 + ((0 * 56 + h) % 3);
      o1 = ((1 * 3 + k1) * 16 + gc) * 58 + ((1 * 56 + h) % 3);
      o2 = ((2 * 3 + k1) * 16 + gc) * 58 + ((2 * 56 + h) % 3);
      o3 = o0;
      dg = 1344 + g * 48 + u;
    }
    tOff[0][dl] = o0; tOff[1][dl] = o1; tOff[2][dl] = o2; tOff[3][dl] = o3;
    tDg[dl] = dg;
  }
  __syncthreads();

  // fill xb: 144 rows x 58 cols, 5 rows per iteration (bit-ops only)
  {
    int wc = t & 63;
    int r0 = t >> 6;                     // 0..4
    const long xbch = ((long)b * 256 + g * 16) * 3136;
#pragma unroll 1
    for (int i = 0; i < 29; ++i) {
      int row = r0 + i * 5;
      if (row < 144 && wc < 58) {
        int kk = row >> 4, ch = row & 15;
        int gr = rowbase[kk], wr = wc - 1;
        float v = 0.f;
        if (gr >= 0 && gr < 56 && wr >= 0 && wr < 56)
          v = x[xbch + ch * 3136 + gr * 56 + wr];
        xb[row * 58 + wc] = v;
      }
    }
  }
  __syncthreads();

  // each active thread owns one dl (fixed offsets), iterates p
  if (t < 264) {
    int p0 = (t >= 132) ? 1 : 0;
    int dl = t - p0 * 132;
    int o0 = tOff[0][dl], o1 = tOff[1][dl], o2 = tOff[2][dl], o3 = tOff[3][dl];
    long dbase = ((long)(b * 56 + h)) * 56 * 2112 + tDg[dl];
#pragma unroll 1
    for (int i = 0; i < 28; ++i) {
      int p = p0 + i * 2;
      float v = fmaxf(fmaxf(xb[o0 + p], xb[o1 + p]), fmaxf(xb[o2 + p], xb[o3 + p]));
      long di = dbase + p * 2112;
      unsigned short hi = f2bf(v);
      descH[di] = hi;
      if (uselo) descL[di] = f2bf(v - bf2f(hi));
    }
  }
}

// ---------------- kGemm1: split-K partial GEMM (M=64, N=96, K-chunk=352) ----------------
// grid = 196 Mtiles x 6 K-chunks = 1176 blocks, 256 threads; all-register, fp32 partials out
__global__ __launch_bounds__(256) void kGemm1(
    const unsigned short* __restrict__ descH, const unsigned short* __restrict__ descL,
    const unsigned short* __restrict__ w1h, const unsigned short* __restrict__ w1l,
    float* __restrict__ pacc, int uselo) {
  const int t = threadIdx.x;
  const int wv = t >> 6, lane = t & 63, quad = lane >> 4, lr = lane & 15;
  const int mt = blockIdx.x / 6, ck = blockIdx.x % 6;
  const long mblk = (long)mt * 64;

  const long abase = (mblk + wv * 16 + lr) * 2112 + ck * 352 + quad * 8;
  const int wb1 = lr * 2112 + ck * 352 + quad * 8;   // + j*33792 + kt*32

  floatx4 zero4 = {0.f, 0.f, 0.f, 0.f};
  floatx4 acc[6];
#pragma unroll
  for (int j = 0; j < 6; ++j) acc[j] = zero4;

  short8 cah, cal, cbh[6], cbl[6];
  cah = *(const short8*)(descH + abase);
  if (uselo) cal = *(const short8*)(descL + abase);
#pragma unroll
  for (int j = 0; j < 6; ++j) {
    cbh[j] = *(const short8*)(w1h + wb1 + j * 33792);
    cbl[j] = *(const short8*)(w1l + wb1 + j * 33792);
  }

  for (int kt = 0; kt < 11; ++kt) {
    short8 nah, nal, nbh[6], nbl[6];
    if (kt < 10) {
      int nx = (kt + 1) * 32;
      nah = *(const short8*)(descH + abase + nx);
      if (uselo) nal = *(const short8*)(descL + abase + nx);
#pragma unroll
      for (int j = 0; j < 6; ++j) {
        nbh[j] = *(const short8*)(w1h + wb1 + j * 33792 + nx);
        nbl[j] = *(const short8*)(w1l + wb1 + j * 33792 + nx);
      }
    }
#pragma unroll
    for (int j = 0; j < 6; ++j) {
      acc[j] = __builtin_amdgcn_mfma_f32_16x16x32_bf16(cah, cbh[j], acc[j], 0, 0, 0);
      acc[j] = __builtin_amdgcn_mfma_f32_16x16x32_bf16(cah, cbl[j], acc[j], 0, 0, 0);
    }
    if (uselo) {
#pragma unroll
      for (int j = 0; j < 6; ++j)
        acc[j] = __builtin_amdgcn_mfma_f32_16x16x32_bf16(cal, cbh[j], acc[j], 0, 0, 0);
    }
    if (kt < 10) {
      cah = nah;
      if (uselo) cal = nal;
#pragma unroll
      for (int j = 0; j < 6; ++j) { cbh[j] = nbh[j]; cbl[j] = nbl[j]; }
    }
  }

  float* pp = pacc + (long)(ck * 196 + mt) * 6144;
#pragma unroll
  for (int j = 0; j < 6; ++j)
#pragma unroll
    for (int r = 0; r < 4; ++r)
      pp[(wv * 16 + quad * 4 + r) * 96 + j * 16 + lr] = acc[j][r];
}

// ---------------- kGemm2: sum partials -> BN/ReLU -> GEMM2 (w2,w3) -> softmax -> wt fp16 ----
// 196 blocks x 256 threads
__global__ __launch_bounds__(256) void kGemm2(
    const float* __restrict__ pacc,
    const unsigned short* __restrict__ w2h, const unsigned short* __restrict__ w2l,
    const unsigned short* __restrict__ w3h, const unsigned short* __restrict__ w3l,
    const float* __restrict__ gamma, const float* __restrict__ beta,
    const float* __restrict__ mean, const float* __restrict__ var,
    const float* __restrict__ b2, const float* __restrict__ b3,
    _Float16* __restrict__ wtg) {
  __shared__ __align__(16) char smem[49152];
  unsigned short* ytH = (unsigned short*)smem;            // 64*104 bf16
  unsigned short* ytL = (unsigned short*)(smem + 13312);  // 64*104 bf16
  float* wal = (float*)smem;                              // phase3: 64*96 f32
  float* wbl = (float*)(smem + 24576);                    // phase3: 64*96 f32
  __shared__ float invv[96], biasv[96];

  const int t = threadIdx.x;
  const int wv = t >> 6, lane = t & 63, quad = lane >> 4, lr = lane & 15;
  const int mt = blockIdx.x;
  const long mblk = (long)mt * 64;

  if (t < 96) {
    float iv = gamma[t] * rsqrtf(var[t] + 1e-5f);
    invv[t] = iv; biasv[t] = beta[t] - mean[t] * iv;
  }

  floatx4 zero4 = {0.f, 0.f, 0.f, 0.f};
  floatx4 acc[6];
#pragma unroll
  for (int j = 0; j < 6; ++j) acc[j] = zero4;
  {
    const float* pb = pacc + (long)mt * 6144 + (wv * 16 + quad * 4) * 96 + lr;
#pragma unroll
    for (int ck = 0; ck < 6; ++ck) {
      const float* pc = pb + (long)ck * 196 * 6144;
#pragma unroll
      for (int j = 0; j < 6; ++j)
#pragma unroll
        for (int r = 0; r < 4; ++r)
          acc[j][r] += pc[r * 96 + j * 16];
    }
  }

  __syncthreads();
#pragma unroll
  for (int j = 0; j < 6; ++j) {
    int n = j * 16 + lr;
    float iv = invv[n], bv = biasv[n];
#pragma unroll
    for (int r = 0; r < 4; ++r) {
      int m = wv * 16 + quad * 4 + r;
      float y = fmaxf(acc[j][r] * iv + bv, 0.f);
      unsigned short hi = f2bf(y);
      ytH[m * 104 + n] = hi;
      ytL[m * 104 + n] = f2bf(y - bf2f(hi));
    }
  }
  __syncthreads();

  floatx4 acc2a[6], acc2b[6];
#pragma unroll
  for (int j = 0; j < 6; ++j) { acc2a[j] = zero4; acc2b[j] = zero4; }
#pragma unroll
  for (int ks = 0; ks < 3; ++ks) {
    short8 afh = *(const short8*)(ytH + (wv * 16 + lr) * 104 + ks * 32 + quad * 8);
    short8 afl = *(const short8*)(ytL + (wv * 16 + lr) * 104 + ks * 32 + quad * 8);
#pragma unroll
    for (int j = 0; j < 6; ++j) {
      int wo = j * 1536 + lr * 96 + ks * 32 + quad * 8;
      short8 bh2 = *(const short8*)(w2h + wo);
      short8 bl2 = *(const short8*)(w2l + wo);
      short8 bh3 = *(const short8*)(w3h + wo);
      short8 bl3 = *(const short8*)(w3l + wo);
      acc2a[j] = __builtin_amdgcn_mfma_f32_16x16x32_bf16(afh, bh2, acc2a[j], 0, 0, 0);
      acc2a[j] = __builtin_amdgcn_mfma_f32_16x16x32_bf16(afl, bh2, acc2a[j], 0, 0, 0);
      acc2a[j] = __builtin_amdgcn_mfma_f32_16x16x32_bf16(afh, bl2, acc2a[j], 0, 0, 0);
      acc2b[j] = __builtin_amdgcn_mfma_f32_16x16x32_bf16(afh, bh3, acc2b[j], 0, 0, 0);
      acc2b[j] = __builtin_amdgcn_mfma_f32_16x16x32_bf16(afl, bh3, acc2b[j], 0, 0, 0);
      acc2b[j] = __builtin_amdgcn_mfma_f32_16x16x32_bf16(afh, bl3, acc2b[j], 0, 0, 0);
    }
  }
  __syncthreads();

#pragma unroll
  for (int j = 0; j < 6; ++j) {
    int n = j * 16 + lr;
    float bb2 = b2[n], bb3 = b3[n];
#pragma unroll
    for (int r = 0; r < 4; ++r) {
      int m = wv * 16 + quad * 4 + r;
      wal[m * 96 + n] = acc2a[j][r] + bb2;
      wbl[m * 96 + n] = acc2b[j][r] + bb3;
    }
  }
  __syncthreads();

  for (int it = 0; it < 16; ++it) {
    int u = t + it * 256;
    int m = u >> 6, rest = u & 63;
    int g = rest >> 2, ns = rest & 3;
    int ns1 = ns >> 1, ns2 = ns & 1;
    float la[3], lb[3];
#pragma unroll
    for (int k = 0; k < 3; ++k) {
      la[k] = wal[m * 96 + (g * 3 + k) * 2 + ns1];
      lb[k] = wbl[m * 96 + (g * 3 + k) * 2 + ns2];
    }
    float lg[9], mx = -1e30f;
#pragma unroll
    for (int k1 = 0; k1 < 3; ++k1)
#pragma unroll
      for (int k2 = 0; k2 < 3; ++k2) {
        float v = la[k1] * lb[k2];
        lg[k1 * 3 + k2] = v;
        mx = v > mx ? v : mx;
      }
    float s = 0.f;
#pragma unroll
    for (int k = 0; k < 9; ++k) { lg[k] = __expf(lg[k] - mx); s += lg[k]; }
    float sc = 1.f / (9.f * s);
    _Float16* dst = wtg + (mblk + m) * 576 + g * 36 + ns * 9;
#pragma unroll
    for (int k = 0; k < 9; ++k) dst[k] = (_Float16)(lg[k] * sc);
  }
}

// ---------------- kGemmMono: fallback monolithic GEMM (round-2 version) ----------------
__global__ __launch_bounds__(256) void kGemmMono(
    const unsigned short* __restrict__ descH, const unsigned short* __restrict__ descL,
    const unsigned short* __restrict__ w1h, const unsigned short* __restrict__ w1l,
    const unsigned short* __restrict__ w2h, const unsigned short* __restrict__ w2l,
    const unsigned short* __restrict__ w3h, const unsigned short* __restrict__ w3l,
    const float* __restrict__ gamma, const float* __restrict__ beta,
    const float* __restrict__ mean, const float* __restrict__ var,
    const float* __restrict__ b2, const float* __restrict__ b3,
    _Float16* __restrict__ wtg, int uselo) {
  __shared__ __align__(16) char smem[49152];
  unsigned short* ytH = (unsigned short*)smem;
  unsigned short* ytL = (unsigned short*)(smem + 13312);
  float* wal = (float*)smem;
  float* wbl = (float*)(smem + 24576);
  __shared__ float invv[96], biasv[96];

  const int t = threadIdx.x;
  const int wv = t >> 6, lane = t & 63, quad = lane >> 4, lr = lane & 15;
  const long mblk = (long)blockIdx.x * 64;

  if (t < 96) {
    float iv = gamma[t] * rsqrtf(var[t] + 1e-5f);
    invv[t] = iv; biasv[t] = beta[t] - mean[t] * iv;
  }

  const long abase = (mblk + wv * 16 + lr) * 2112 + quad * 8;
  const int wb1 = lr * 2112 + quad * 8;

  floatx4 zero4 = {0.f, 0.f, 0.f, 0.f};
  floatx4 acc[6];
#pragma unroll
  for (int j = 0; j < 6; ++j) acc[j] = zero4;

  short8 cah, cal, cbh[6], cbl[6];
  cah = *(const short8*)(descH + abase);
  if (uselo) cal = *(const short8*)(descL + abase);
#pragma unroll
  for (int j = 0; j < 6; ++j) {
    cbh[j] = *(const short8*)(w1h + wb1 + j * 33792);
    cbl[j] = *(const short8*)(w1l + wb1 + j * 33792);
  }
  for (int kt = 0; kt < 66; ++kt) {
    short8 nah, nal, nbh[6], nbl[6];
    if (kt < 65) {
      int nx = (kt + 1) * 32;
      nah = *(const short8*)(descH + abase + nx);
      if (uselo) nal = *(const short8*)(descL + abase + nx);
#pragma unroll
      for (int j = 0; j < 6; ++j) {
        nbh[j] = *(const short8*)(w1h + wb1 + j * 33792 + nx);
        nbl[j] = *(const short8*)(w1l + wb1 + j * 33792 + nx);
      }
    }
#pragma unroll
    for (int j = 0; j < 6; ++j) {
      acc[j] = __builtin_amdgcn_mfma_f32_16x16x32_bf16(cah, cbh[j], acc[j], 0, 0, 0);
      acc[j] = __builtin_amdgcn_mfma_f32_16x16x32_bf16(cah, cbl[j], acc[j], 0, 0, 0);
    }
    if (uselo) {
#pragma unroll
      for (int j = 0; j < 6; ++j)
        acc[j] = __builtin_amdgcn_mfma_f32_16x16x32_bf16(cal, cbh[j], acc[j], 0, 0, 0);
    }
    if (kt < 65) {
      cah = nah;
      if (uselo) cal = nal;
#pragma unroll
      for (int j = 0; j < 6; ++j) { cbh[j] = nbh[j]; cbl[j] = nbl[j]; }
    }
  }

  __syncthreads();
#pragma unroll
  for (int j = 0; j < 6; ++j) {
    int n = j * 16 + lr;
    float iv = invv[n], bv = biasv[n];
#pragma unroll
    for (int r = 0; r < 4; ++r) {
      int m = wv * 16 + quad * 4 + r;
      float y = fmaxf(acc[j][r] * iv + bv, 0.f);
      unsigned short hi = f2bf(y);
      ytH[m * 104 + n] = hi;
      ytL[m * 104 + n] = f2bf(y - bf2f(hi));
    }
  }
  __syncthreads();

  floatx4 acc2a[6], acc2b[6];
#pragma unroll
  for (int j = 0; j < 6; ++j) { acc2a[j] = zero4; acc2b[j] = zero4; }
#pragma unroll
  for (int ks = 0; ks < 3; ++ks) {
    short8 afh = *(const short8*)(ytH + (wv * 16 + lr) * 104 + ks * 32 + quad * 8);
    short8 afl = *(const short8*)(ytL + (wv * 16 + lr) * 104 + ks * 32 + quad * 8);
#pragma unroll
    for (int j = 0; j < 6; ++j) {
      int wo = j * 1536 + lr * 96 + ks * 32 + quad * 8;
      short8 bh2 = *(const short8*)(w2h + wo);
      short8 bl2 = *(const short8*)(w2l + wo);
      short8 bh3 = *(const short8*)(w3h + wo);
      short8 bl3 = *(const short8*)(w3l + wo);
      acc2a[j] = __builtin_amdgcn_mfma_f32_16x16x32_bf16(afh, bh2, acc2a[j], 0, 0, 0);
      acc2a[j] = __builtin_amdgcn_mfma_f32_16x16x32_bf16(afl, bh2, acc2a[j], 0, 0, 0);
      acc2a[j] = __builtin_amdgcn_mfma_f32_16x16x32_bf16(afh, bl2, acc2a[j], 0, 0, 0);
      acc2b[j] = __builtin_amdgcn_mfma_f32_16x16x32_bf16(afh, bh3, acc2b[j], 0, 0, 0);
      acc2b[j] = __builtin_amdgcn_mfma_f32_16x16x32_bf16(afl, bh3, acc2b[j], 0, 0, 0);
      acc2b[j] = __builtin_amdgcn_mfma_f32_16x16x32_bf16(afh, bl3, acc2b[j], 0, 0, 0);
    }
  }
  __syncthreads();
#pragma unroll
  for (int j = 0; j < 6; ++j) {
    int n = j * 16 + lr;
    float bb2 = b2[n], bb3 = b3[n];
#pragma unroll
    for (int r = 0; r < 4; ++r) {
      int m = wv * 16 + quad * 4 + r;
      wal[m * 96 + n] = acc2a[j][r] + bb2;
      wbl[m * 96 + n] = acc2b[j][r] + bb3;
    }
  }
  __syncthreads();
  for (int it = 0; it < 16; ++it) {
    int u = t + it * 256;
    int m = u >> 6, rest = u & 63;
    int g = rest >> 2, ns = rest & 3;
    int ns1 = ns >> 1, ns2 = ns & 1;
    float la[3], lb[3];
#pragma unroll
    for (int k = 0; k < 3; ++k) {
      la[k] = wal[m * 96 + (g * 3 + k) * 2 + ns1];
      lb[k] = wbl[m * 96 + (g * 3 + k) * 2 + ns2];
    }
    float lg[9], mx = -1e30f;
#pragma unroll
    for (int k1 = 0; k1 < 3; ++k1)
#pragma unroll
      for (int k2 = 0; k2 < 3; ++k2) {
        float v = la[k1] * lb[k2];
        lg[k1 * 3 + k2] = v;
        mx = v > mx ? v : mx;
      }
    float s = 0.f;
#pragma unroll
    for (int k = 0; k < 9; ++k) { lg[k] = __expf(lg[k] - mx); s += lg[k]; }
    float sc = 1.f / (9.f * s);
    _Float16* dst = wtg + (mblk + m) * 576 + g * 36 + ns * 9;
#pragma unroll
    for (int k = 0; k < 9; ++k) dst[k] = (_Float16)(lg[k] * sc);
  }
}

// ---------------- kApply: x + wt -> out (padded LDS, branch-free index math) ----------
// block = (b, h', wh(2), cq(8)): 3584 blocks, 256 threads; 32 channels, 28 w-positions
__global__ __launch_bounds__(256) void kApply(const float* __restrict__ x,
                                              const _Float16* __restrict__ wt,
                                              float* __restrict__ out) {
  int bid = blockIdx.x;
  int cq = bid & 7;
  int wh = (bid >> 3) & 1;
  int h = (bid >> 4) % 56;
  int b = bid / 896;
  int wbase = wh * 28, cbase = cq * 32;

  __shared__ float xr[9 * 32 * 33];   // [kk*1056 + cl*33 + wc], wc<30 used
  __shared__ float wtb[28 * 72];      // [p*72 + gp*36 + ns*9 + k1*3+k2]
  __shared__ float ob[64 * 56];       // [(cl*2+ns1)*56 + wout]
  __shared__ int rowbase[9];

  int t = threadIdx.x;
  if (t < 9) {
    int k2 = t / 3, k1 = t % 3;
    rowbase[t] = (k2 * 56 + h) / 3 + k1 - 1;
  }
  int j2r[3];
#pragma unroll
  for (int k2 = 0; k2 < 3; ++k2) j2r[k2] = (k2 * 56 + h) % 3;
  __syncthreads();

  // fill xr: 288 rows (kk,cl) x 30 cols; 8 rows/iter, bit-ops only
  {
    int wc = t & 31;
    int r0 = t >> 5;                    // 0..7
    const long xbch = ((long)b * 256 + cbase) * 3136;
#pragma unroll 1
    for (int i = 0; i < 36; ++i) {
      int row = r0 + i * 8;
      if (wc < 30) {
        int kk = row >> 5, cl = row & 31;
        int gr = rowbase[kk], wr = wbase + wc - 1;
        float v = 0.f;
        if (gr >= 0 && gr < 56 && wr >= 0 && wr < 56)
          v = x[xbch + cl * 3136 + gr * 56 + wr];
        xr[kk * 1056 + cl * 33 + wc] = v;
      }
    }
  }
  {
    long m0 = ((long)(b * 56 + h)) * 56 + wbase;
    for (int idx = t; idx < 2016; idx += 256) {
      int p = idx / 72, rem = idx % 72;
      wtb[idx] = (float)wt[(m0 + p) * 576 + cq * 72 + rem];
    }
  }
  __syncthreads();

  int cl = (t & 127) >> 2;
  int ns = t & 3;
  int ns1 = ns >> 1, ns2 = ns & 1;
  int psel = t >> 7;
  int gp = cl >> 4;
  int a2k[3];
#pragma unroll
  for (int k2 = 0; k2 < 3; ++k2) a2k[k2] = k2 * 3168 + cl * 33 + j2r[k2];
  int wtbase = gp * 36 + ns * 9;
  int obbase = (cl * 2 + ns1) * 56 + ns2;
#pragma unroll 1
  for (int it = 0; it < 14; ++it) {
    int p = it * 2 + psel;
    float accv = 0.f;
    int wpb = p * 72 + wtbase;
#pragma unroll
    for (int k1 = 0; k1 < 3; ++k1)
#pragma unroll
      for (int k2 = 0; k2 < 3; ++k2)
        accv += xr[a2k[k2] + k1 * 1056 + p] * wtb[wpb + k1 * 3 + k2];
    ob[obbase + p * 2] = accv;
  }
  __syncthreads();

  // writeout: 64 rows x 56 cols; 4 rows/iter, bit-ops only
  {
    int wo = t & 63;
    int r0 = t >> 6;                    // 0..3
    const long obase = (((long)b * 256 + cbase) * 112 + 2 * h) * 112 + wh * 56;
#pragma unroll 1
    for (int i = 0; i < 16; ++i) {
      int row = r0 + i * 4;
      if (wo < 56) {
        int cli = row >> 1, n1 = row & 1;
        out[obase + cli * 12544 + n1 * 112 + wo] = ob[row * 56 + wo];
      }
    }
  }
}

extern "C" void kernel_launch(void* const* d_in, const int* in_sizes, int n_in,
                              void* d_out, int out_size, void* d_ws, size_t ws_size,
                              hipStream_t stream) {
  const float* x = (const float*)d_in[0];
  const float* w1 = (const float*)d_in[1];
  const float* gamma = (const float*)d_in[2];
  const float* beta = (const float*)d_in[3];
  const float* mean = (const float*)d_in[4];
  const float* var = (const float*)d_in[5];
  const float* w2 = (const float*)d_in[6];
  const float* b2 = (const float*)d_in[7];
  const float* w3 = (const float*)d_in[8];
  const float* b3 = (const float*)d_in[9];
  float* out = (float*)d_out;

  // workspace layout (bytes):
  //   weights hi/lo:   [0, 884736)
  //   wtg fp16:        [884736, 15335424)
  //   descH bf16:      [15335424, 68321280)
  //   descL bf16:      [68321280, 121307136)
  //   pacc fp32:       [121307136, 150208512)   (split-K partials)
  unsigned short* w1h = (unsigned short*)d_ws;
  unsigned short* w1l = w1h + 202752;
  unsigned short* w2h = w1l + 202752;
  unsigned short* w2l = w2h + 9216;
  unsigned short* w3h = w2l + 9216;
  unsigned short* w3l = w3h + 9216;
  _Float16* wtg = (_Float16*)((char*)d_ws + 884736);
  unsigned short* descH = (unsigned short*)((char*)d_ws + 15335424);
  unsigned short* descL = descH + 26492928;
  float* pacc = (float*)((char*)d_ws + 121307136);
  int uselo = (ws_size >= (size_t)121307136) ? 1 : 0;
  int splitk = (ws_size >= (size_t)150208512) ? 1 : 0;

  hipLaunchKernelGGL(kW, dim3(864), dim3(256), 0, stream,
                     w1, w2, w3, w1h, w1l, w2h, w2l, w3h, w3l);
  hipLaunchKernelGGL(kDesc, dim3(3584), dim3(320), 0, stream, x, descH, descL, uselo);
  if (splitk) {
    hipLaunchKernelGGL(kGemm1, dim3(1176), dim3(256), 0, stream,
                       descH, descL, w1h, w1l, pacc, uselo);
    hipLaunchKernelGGL(kGemm2, dim3(196), dim3(256), 0, stream,
                       pacc, w2h, w2l, w3h, w3l,
                       gamma, beta, mean, var, b2, b3, wtg);
  } else {
    hipLaunchKernelGGL(kGemmMono, dim3(196), dim3(256), 0, stream,
                       descH, descL, w1h, w1l, w2h, w2l, w3h, w3l,
                       gamma, beta, mean, var, b2, b3, wtg, uselo);
  }
  hipLaunchKernelGGL(kApply, dim3(3584), dim3(256), 0, stream, x, wtg, out);
}

// Round 4
// 323.895 us; speedup vs baseline: 1.3202x; 1.3202x over previous
//
#include <hip/hip_runtime.h>

typedef __attribute__((ext_vector_type(8))) short short8;
typedef __attribute__((ext_vector_type(4))) float floatx4;

__device__ inline unsigned short f2bf(float f) {
  union { float f; unsigned int u; } c; c.f = f;
  unsigned int u = c.u;
  return (unsigned short)((u + 0x7fffu + ((u >> 16) & 1u)) >> 16);
}
__device__ inline float bf2f(unsigned short h) {
  union { unsigned int u; float f; } c; c.u = ((unsigned int)h) << 16;
  return c.f;
}

// ---------------- kW: fp32 -> (bf16-hi, bf16-lo) weight planes ----------------
__global__ __launch_bounds__(256) void kW(const float* __restrict__ w1,
                                          const float* __restrict__ w2,
                                          const float* __restrict__ w3,
                                          unsigned short* __restrict__ w1h,
                                          unsigned short* __restrict__ w1l,
                                          unsigned short* __restrict__ w2h,
                                          unsigned short* __restrict__ w2l,
                                          unsigned short* __restrict__ w3h,
                                          unsigned short* __restrict__ w3l) {
  int i = blockIdx.x * 256 + threadIdx.x;
  if (i < 202752) {
    float v = w1[i]; unsigned short hi = f2bf(v);
    w1h[i] = hi; w1l[i] = f2bf(v - bf2f(hi));
  } else if (i < 211968) {
    int k = i - 202752;
    float v = w2[k]; unsigned short hi = f2bf(v);
    w2h[k] = hi; w2l[k] = f2bf(v - bf2f(hi));
  } else if (i < 221184) {
    int k = i - 211968;
    float v = w3[k]; unsigned short hi = f2bf(v);
    w3h[k] = hi; w3l[k] = f2bf(v - bf2f(hi));
  }
}

// ---------------- kDesc: scrambled-unfold descriptors -> desc [12544, 2112] hi/lo bf16 ----
// tap(k1,k2) at (h',w') = x[row=(k2*56+h')/3+k1-1, col=w'+(k2*56+h')%3-1], zero-pad.
// block=(b,h',g): 3584 blocks, 320 threads. Fully-unrolled loops for memory-level parallelism.
__global__ __launch_bounds__(320) void kDesc(const float* __restrict__ x,
                                             unsigned short* __restrict__ descH,
                                             unsigned short* __restrict__ descL,
                                             int uselo) {
  int bid = blockIdx.x;
  int g = bid & 15;
  int h = (bid >> 4) % 56;
  int b = bid / 896;
  __shared__ float xb[144 * 58];        // [(kk*16+ch)*58 + wc], kk=k2*3+k1
  __shared__ int tOff[4][132];          // 4 LDS offsets per dl
  __shared__ int tDg[132];              // dglob per dl

  int t = threadIdx.x;
  if (t < 132) {
    int dl = t;
    int o0, o1, o2, o3, dg;
    if (dl < 36) {                       // x1: max over 4 sub-channels
      int a3 = dl / 9, rem = dl % 9, k1 = rem / 3, k2 = rem % 3;
      int j2k = (k2 * 56 + h) % 3;
      int base = (k2 * 3 + k1) * 16;
      o0 = (base + a3) * 58 + j2k;
      o1 = (base + 4 + a3) * 58 + j2k;
      o2 = (base + 8 + a3) * 58 + j2k;
      o3 = (base + 12 + a3) * 58 + j2k;
      dg = g * 36 + dl;
    } else if (dl < 84) {                // x2: max over k1
      int u = dl - 36, gc = u / 3, k2 = u % 3;
      int j2k = (k2 * 56 + h) % 3;
      o0 = ((k2 * 3 + 0) * 16 + gc) * 58 + j2k;
      o1 = ((k2 * 3 + 1) * 16 + gc) * 58 + j2k;
      o2 = ((k2 * 3 + 2) * 16 + gc) * 58 + j2k;
      o3 = o0;
      dg = 576 + g * 48 + u;
    } else {                             // x3: max over k2
      int u = dl - 84, gc = u / 3, k1 = u % 3;
      o0 = ((0 * 3 + k1) * 16 + gc) * 58 + ((0 * 56 + h) % 3);
      o1 = ((1 * 3 + k1) * 16 + gc) * 58 + ((1 * 56 + h) % 3);
      o2 = ((2 * 3 + k1) * 16 + gc) * 58 + ((2 * 56 + h) % 3);
      o3 = o0;
      dg = 1344 + g * 48 + u;
    }
    tOff[0][dl] = o0; tOff[1][dl] = o1; tOff[2][dl] = o2; tOff[3][dl] = o3;
    tDg[dl] = dg;
  }

  // fill xb: 144 rows x 58 cols, batched loads (chunks of 10) for MLP
  {
    int wc = t & 63;
    int r0 = t >> 6;                     // 0..4
    int wr = wc - 1;
    bool wok = (wc < 58) & (wr >= 0) & (wr < 56);
    const long xb0 = ((long)b * 256 + g * 16) * 3136;
#pragma unroll
    for (int ch_ = 0; ch_ < 3; ++ch_) {
      const int nI = (ch_ < 2) ? 10 : 9;
      float vals[10];
#pragma unroll
      for (int i = 0; i < nI; ++i) {
        int row = r0 + (ch_ * 10 + i) * 5;
        int kk = row >> 4, ch = row & 15;
        int k2 = kk / 3, k1 = kk - 3 * k2;
        int gr = (k2 * 56 + h) / 3 + k1 - 1;
        float v = 0.f;
        if (wok && row < 144 && gr >= 0 && gr < 56)
          v = x[xb0 + ch * 3136 + (long)gr * 56 + wr];
        vals[i] = v;
      }
#pragma unroll
      for (int i = 0; i < nI; ++i) {
        int row = r0 + (ch_ * 10 + i) * 5;
        if (row < 144 && wc < 58) xb[row * 58 + wc] = vals[i];
      }
    }
  }
  __syncthreads();

  // each active thread owns one dl (fixed offsets), iterates p — fully unrolled
  if (t < 264) {
    int p0 = (t >= 132) ? 1 : 0;
    int dl = t - p0 * 132;
    int o0 = tOff[0][dl], o1 = tOff[1][dl], o2 = tOff[2][dl], o3 = tOff[3][dl];
    long dbase = ((long)(b * 56 + h)) * 56 * 2112 + tDg[dl];
#pragma unroll
    for (int i = 0; i < 28; ++i) {
      int p = p0 + i * 2;
      float v = fmaxf(fmaxf(xb[o0 + p], xb[o1 + p]), fmaxf(xb[o2 + p], xb[o3 + p]));
      long di = dbase + (long)p * 2112;
      unsigned short hi = f2bf(v);
      descH[di] = hi;
      if (uselo) descL[di] = f2bf(v - bf2f(hi));
    }
  }
}

// ---------------- kGemm1: split-K partial GEMM (M=64, N=96, K-chunk=352) ----------------
// grid = 196 Mtiles x 6 K-chunks = 1176 blocks, 256 threads; all-register, fp32 partials out
__global__ __launch_bounds__(256) void kGemm1(
    const unsigned short* __restrict__ descH, const unsigned short* __restrict__ descL,
    const unsigned short* __restrict__ w1h, const unsigned short* __restrict__ w1l,
    float* __restrict__ pacc, int uselo) {
  const int t = threadIdx.x;
  const int wv = t >> 6, lane = t & 63, quad = lane >> 4, lr = lane & 15;
  const int mt = blockIdx.x / 6, ck = blockIdx.x % 6;
  const long mblk = (long)mt * 64;

  const long abase = (mblk + wv * 16 + lr) * 2112 + ck * 352 + quad * 8;
  const int wb1 = lr * 2112 + ck * 352 + quad * 8;   // + j*33792 + kt*32

  floatx4 zero4 = {0.f, 0.f, 0.f, 0.f};
  floatx4 acc[6];
#pragma unroll
  for (int j = 0; j < 6; ++j) acc[j] = zero4;

  short8 cah, cal, cbh[6], cbl[6];
  cah = *(const short8*)(descH + abase);
  if (uselo) cal = *(const short8*)(descL + abase);
#pragma unroll
  for (int j = 0; j < 6; ++j) {
    cbh[j] = *(const short8*)(w1h + wb1 + j * 33792);
    cbl[j] = *(const short8*)(w1l + wb1 + j * 33792);
  }

  for (int kt = 0; kt < 11; ++kt) {
    short8 nah, nal, nbh[6], nbl[6];
    if (kt < 10) {
      int nx = (kt + 1) * 32;
      nah = *(const short8*)(descH + abase + nx);
      if (uselo) nal = *(const short8*)(descL + abase + nx);
#pragma unroll
      for (int j = 0; j < 6; ++j) {
        nbh[j] = *(const short8*)(w1h + wb1 + j * 33792 + nx);
        nbl[j] = *(const short8*)(w1l + wb1 + j * 33792 + nx);
      }
    }
#pragma unroll
    for (int j = 0; j < 6; ++j) {
      acc[j] = __builtin_amdgcn_mfma_f32_16x16x32_bf16(cah, cbh[j], acc[j], 0, 0, 0);
      acc[j] = __builtin_amdgcn_mfma_f32_16x16x32_bf16(cah, cbl[j], acc[j], 0, 0, 0);
    }
    if (uselo) {
#pragma unroll
      for (int j = 0; j < 6; ++j)
        acc[j] = __builtin_amdgcn_mfma_f32_16x16x32_bf16(cal, cbh[j], acc[j], 0, 0, 0);
    }
    if (kt < 10) {
      cah = nah;
      if (uselo) cal = nal;
#pragma unroll
      for (int j = 0; j < 6; ++j) { cbh[j] = nbh[j]; cbl[j] = nbl[j]; }
    }
  }

  float* pp = pacc + (long)(ck * 196 + mt) * 6144;
#pragma unroll
  for (int j = 0; j < 6; ++j)
#pragma unroll
    for (int r = 0; r < 4; ++r)
      pp[(wv * 16 + quad * 4 + r) * 96 + j * 16 + lr] = acc[j][r];
}

// ---------------- kGemm2: sum partials -> BN/ReLU -> GEMM2 (w2,w3) -> softmax -> wt fp16 ----
// 196 blocks x 256 threads
__global__ __launch_bounds__(256) void kGemm2(
    const float* __restrict__ pacc,
    const unsigned short* __restrict__ w2h, const unsigned short* __restrict__ w2l,
    const unsigned short* __restrict__ w3h, const unsigned short* __restrict__ w3l,
    const float* __restrict__ gamma, const float* __restrict__ beta,
    const float* __restrict__ mean, const float* __restrict__ var,
    const float* __restrict__ b2, const float* __restrict__ b3,
    _Float16* __restrict__ wtg) {
  __shared__ __align__(16) char smem[49152];
  unsigned short* ytH = (unsigned short*)smem;            // 64*104 bf16
  unsigned short* ytL = (unsigned short*)(smem + 13312);  // 64*104 bf16
  float* wal = (float*)smem;                              // phase3: 64*96 f32
  float* wbl = (float*)(smem + 24576);                    // phase3: 64*96 f32
  __shared__ float invv[96], biasv[96];

  const int t = threadIdx.x;
  const int wv = t >> 6, lane = t & 63, quad = lane >> 4, lr = lane & 15;
  const int mt = blockIdx.x;
  const long mblk = (long)mt * 64;

  if (t < 96) {
    float iv = gamma[t] * rsqrtf(var[t] + 1e-5f);
    invv[t] = iv; biasv[t] = beta[t] - mean[t] * iv;
  }

  floatx4 zero4 = {0.f, 0.f, 0.f, 0.f};
  floatx4 acc[6];
#pragma unroll
  for (int j = 0; j < 6; ++j) acc[j] = zero4;
  {
    const float* pb = pacc + (long)mt * 6144 + (wv * 16 + quad * 4) * 96 + lr;
#pragma unroll
    for (int ck = 0; ck < 6; ++ck) {
      const float* pc = pb + (long)ck * 196 * 6144;
#pragma unroll
      for (int j = 0; j < 6; ++j)
#pragma unroll
        for (int r = 0; r < 4; ++r)
          acc[j][r] += pc[r * 96 + j * 16];
    }
  }

  __syncthreads();
#pragma unroll
  for (int j = 0; j < 6; ++j) {
    int n = j * 16 + lr;
    float iv = invv[n], bv = biasv[n];
#pragma unroll
    for (int r = 0; r < 4; ++r) {
      int m = wv * 16 + quad * 4 + r;
      float y = fmaxf(acc[j][r] * iv + bv, 0.f);
      unsigned short hi = f2bf(y);
      ytH[m * 104 + n] = hi;
      ytL[m * 104 + n] = f2bf(y - bf2f(hi));
    }
  }
  __syncthreads();

  floatx4 acc2a[6], acc2b[6];
#pragma unroll
  for (int j = 0; j < 6; ++j) { acc2a[j] = zero4; acc2b[j] = zero4; }
#pragma unroll
  for (int ks = 0; ks < 3; ++ks) {
    short8 afh = *(const short8*)(ytH + (wv * 16 + lr) * 104 + ks * 32 + quad * 8);
    short8 afl = *(const short8*)(ytL + (wv * 16 + lr) * 104 + ks * 32 + quad * 8);
#pragma unroll
    for (int j = 0; j < 6; ++j) {
      int wo = j * 1536 + lr * 96 + ks * 32 + quad * 8;
      short8 bh2 = *(const short8*)(w2h + wo);
      short8 bl2 = *(const short8*)(w2l + wo);
      short8 bh3 = *(const short8*)(w3h + wo);
      short8 bl3 = *(const short8*)(w3l + wo);
      acc2a[j] = __builtin_amdgcn_mfma_f32_16x16x32_bf16(afh, bh2, acc2a[j], 0, 0, 0);
      acc2a[j] = __builtin_amdgcn_mfma_f32_16x16x32_bf16(afl, bh2, acc2a[j], 0, 0, 0);
      acc2a[j] = __builtin_amdgcn_mfma_f32_16x16x32_bf16(afh, bl2, acc2a[j], 0, 0, 0);
      acc2b[j] = __builtin_amdgcn_mfma_f32_16x16x32_bf16(afh, bh3, acc2b[j], 0, 0, 0);
      acc2b[j] = __builtin_amdgcn_mfma_f32_16x16x32_bf16(afl, bh3, acc2b[j], 0, 0, 0);
      acc2b[j] = __builtin_amdgcn_mfma_f32_16x16x32_bf16(afh, bl3, acc2b[j], 0, 0, 0);
    }
  }
  __syncthreads();

#pragma unroll
  for (int j = 0; j < 6; ++j) {
    int n = j * 16 + lr;
    float bb2 = b2[n], bb3 = b3[n];
#pragma unroll
    for (int r = 0; r < 4; ++r) {
      int m = wv * 16 + quad * 4 + r;
      wal[m * 96 + n] = acc2a[j][r] + bb2;
      wbl[m * 96 + n] = acc2b[j][r] + bb3;
    }
  }
  __syncthreads();

  for (int it = 0; it < 16; ++it) {
    int u = t + it * 256;
    int m = u >> 6, rest = u & 63;
    int g = rest >> 2, ns = rest & 3;
    int ns1 = ns >> 1, ns2 = ns & 1;
    float la[3], lb[3];
#pragma unroll
    for (int k = 0; k < 3; ++k) {
      la[k] = wal[m * 96 + (g * 3 + k) * 2 + ns1];
      lb[k] = wbl[m * 96 + (g * 3 + k) * 2 + ns2];
    }
    float lg[9], mx = -1e30f;
#pragma unroll
    for (int k1 = 0; k1 < 3; ++k1)
#pragma unroll
      for (int k2 = 0; k2 < 3; ++k2) {
        float v = la[k1] * lb[k2];
        lg[k1 * 3 + k2] = v;
        mx = v > mx ? v : mx;
      }
    float s = 0.f;
#pragma unroll
    for (int k = 0; k < 9; ++k) { lg[k] = __expf(lg[k] - mx); s += lg[k]; }
    float sc = 1.f / (9.f * s);
    _Float16* dst = wtg + (mblk + m) * 576 + g * 36 + ns * 9;
#pragma unroll
    for (int k = 0; k < 9; ++k) dst[k] = (_Float16)(lg[k] * sc);
  }
}

// ---------------- kGemmMono: fallback monolithic GEMM ----------------
__global__ __launch_bounds__(256) void kGemmMono(
    const unsigned short* __restrict__ descH, const unsigned short* __restrict__ descL,
    const unsigned short* __restrict__ w1h, const unsigned short* __restrict__ w1l,
    const unsigned short* __restrict__ w2h, const unsigned short* __restrict__ w2l,
    const unsigned short* __restrict__ w3h, const unsigned short* __restrict__ w3l,
    const float* __restrict__ gamma, const float* __restrict__ beta,
    const float* __restrict__ mean, const float* __restrict__ var,
    const float* __restrict__ b2, const float* __restrict__ b3,
    _Float16* __restrict__ wtg, int uselo) {
  __shared__ __align__(16) char smem[49152];
  unsigned short* ytH = (unsigned short*)smem;
  unsigned short* ytL = (unsigned short*)(smem + 13312);
  float* wal = (float*)smem;
  float* wbl = (float*)(smem + 24576);
  __shared__ float invv[96], biasv[96];

  const int t = threadIdx.x;
  const int wv = t >> 6, lane = t & 63, quad = lane >> 4, lr = lane & 15;
  const long mblk = (long)blockIdx.x * 64;

  if (t < 96) {
    float iv = gamma[t] * rsqrtf(var[t] + 1e-5f);
    invv[t] = iv; biasv[t] = beta[t] - mean[t] * iv;
  }

  const long abase = (mblk + wv * 16 + lr) * 2112 + quad * 8;
  const int wb1 = lr * 2112 + quad * 8;

  floatx4 zero4 = {0.f, 0.f, 0.f, 0.f};
  floatx4 acc[6];
#pragma unroll
  for (int j = 0; j < 6; ++j) acc[j] = zero4;

  short8 cah, cal, cbh[6], cbl[6];
  cah = *(const short8*)(descH + abase);
  if (uselo) cal = *(const short8*)(descL + abase);
#pragma unroll
  for (int j = 0; j < 6; ++j) {
    cbh[j] = *(const short8*)(w1h + wb1 + j * 33792);
    cbl[j] = *(const short8*)(w1l + wb1 + j * 33792);
  }
  for (int kt = 0; kt < 66; ++kt) {
    short8 nah, nal, nbh[6], nbl[6];
    if (kt < 65) {
      int nx = (kt + 1) * 32;
      nah = *(const short8*)(descH + abase + nx);
      if (uselo) nal = *(const short8*)(descL + abase + nx);
#pragma unroll
      for (int j = 0; j < 6; ++j) {
        nbh[j] = *(const short8*)(w1h + wb1 + j * 33792 + nx);
        nbl[j] = *(const short8*)(w1l + wb1 + j * 33792 + nx);
      }
    }
#pragma unroll
    for (int j = 0; j < 6; ++j) {
      acc[j] = __builtin_amdgcn_mfma_f32_16x16x32_bf16(cah, cbh[j], acc[j], 0, 0, 0);
      acc[j] = __builtin_amdgcn_mfma_f32_16x16x32_bf16(cah, cbl[j], acc[j], 0, 0, 0);
    }
    if (uselo) {
#pragma unroll
      for (int j = 0; j < 6; ++j)
        acc[j] = __builtin_amdgcn_mfma_f32_16x16x32_bf16(cal, cbh[j], acc[j], 0, 0, 0);
    }
    if (kt < 65) {
      cah = nah;
      if (uselo) cal = nal;
#pragma unroll
      for (int j = 0; j < 6; ++j) { cbh[j] = nbh[j]; cbl[j] = nbl[j]; }
    }
  }

  __syncthreads();
#pragma unroll
  for (int j = 0; j < 6; ++j) {
    int n = j * 16 + lr;
    float iv = invv[n], bv = biasv[n];
#pragma unroll
    for (int r = 0; r < 4; ++r) {
      int m = wv * 16 + quad * 4 + r;
      float y = fmaxf(acc[j][r] * iv + bv, 0.f);
      unsigned short hi = f2bf(y);
      ytH[m * 104 + n] = hi;
      ytL[m * 104 + n] = f2bf(y - bf2f(hi));
    }
  }
  __syncthreads();

  floatx4 acc2a[6], acc2b[6];
#pragma unroll
  for (int j = 0; j < 6; ++j) { acc2a[j] = zero4; acc2b[j] = zero4; }
#pragma unroll
  for (int ks = 0; ks < 3; ++ks) {
    short8 afh = *(const short8*)(ytH + (wv * 16 + lr) * 104 + ks * 32 + quad * 8);
    short8 afl = *(const short8*)(ytL + (wv * 16 + lr) * 104 + ks * 32 + quad * 8);
#pragma unroll
    for (int j = 0; j < 6; ++j) {
      int wo = j * 1536 + lr * 96 + ks * 32 + quad * 8;
      short8 bh2 = *(const short8*)(w2h + wo);
      short8 bl2 = *(const short8*)(w2l + wo);
      short8 bh3 = *(const short8*)(w3h + wo);
      short8 bl3 = *(const short8*)(w3l + wo);
      acc2a[j] = __builtin_amdgcn_mfma_f32_16x16x32_bf16(afh, bh2, acc2a[j], 0, 0, 0);
      acc2a[j] = __builtin_amdgcn_mfma_f32_16x16x32_bf16(afl, bh2, acc2a[j], 0, 0, 0);
      acc2a[j] = __builtin_amdgcn_mfma_f32_16x16x32_bf16(afh, bl2, acc2a[j], 0, 0, 0);
      acc2b[j] = __builtin_amdgcn_mfma_f32_16x16x32_bf16(afh, bh3, acc2b[j], 0, 0, 0);
      acc2b[j] = __builtin_amdgcn_mfma_f32_16x16x32_bf16(afl, bh3, acc2b[j], 0, 0, 0);
      acc2b[j] = __builtin_amdgcn_mfma_f32_16x16x32_bf16(afh, bl3, acc2b[j], 0, 0, 0);
    }
  }
  __syncthreads();
#pragma unroll
  for (int j = 0; j < 6; ++j) {
    int n = j * 16 + lr;
    float bb2 = b2[n], bb3 = b3[n];
#pragma unroll
    for (int r = 0; r < 4; ++r) {
      int m = wv * 16 + quad * 4 + r;
      wal[m * 96 + n] = acc2a[j][r] + bb2;
      wbl[m * 96 + n] = acc2b[j][r] + bb3;
    }
  }
  __syncthreads();
  for (int it = 0; it < 16; ++it) {
    int u = t + it * 256;
    int m = u >> 6, rest = u & 63;
    int g = rest >> 2, ns = rest & 3;
    int ns1 = ns >> 1, ns2 = ns & 1;
    float la[3], lb[3];
#pragma unroll
    for (int k = 0; k < 3; ++k) {
      la[k] = wal[m * 96 + (g * 3 + k) * 2 + ns1];
      lb[k] = wbl[m * 96 + (g * 3 + k) * 2 + ns2];
    }
    float lg[9], mx = -1e30f;
#pragma unroll
    for (int k1 = 0; k1 < 3; ++k1)
#pragma unroll
      for (int k2 = 0; k2 < 3; ++k2) {
        float v = la[k1] * lb[k2];
        lg[k1 * 3 + k2] = v;
        mx = v > mx ? v : mx;
      }
    float s = 0.f;
#pragma unroll
    for (int k = 0; k < 9; ++k) { lg[k] = __expf(lg[k] - mx); s += lg[k]; }
    float sc = 1.f / (9.f * s);
    _Float16* dst = wtg + (mblk + m) * 576 + g * 36 + ns * 9;
#pragma unroll
    for (int k = 0; k < 9; ++k) dst[k] = (_Float16)(lg[k] * sc);
  }
}

// ---------------- kApply: x + wt -> out ----------
// block = (b, h', wh(2), cq(8)): 3584 blocks, 256 threads; 32 channels, 28 w-positions
// fp16 xr (stride 30, conflict-free), ob stride 57 (conflict-free), batched fill loads.
// LDS = 17280 + 8064 + 14592 = 39936 B -> 4 blocks/CU.
__global__ __launch_bounds__(256) void kApply(const float* __restrict__ x,
                                              const _Float16* __restrict__ wt,
                                              float* __restrict__ out) {
  int bid = blockIdx.x;
  int cq = bid & 7;
  int wh = (bid >> 3) & 1;
  int h = (bid >> 4) % 56;
  int b = bid / 896;
  int wbase = wh * 28, cbase = cq * 32;

  __shared__ _Float16 xr[9 * 32 * 30];  // [kk*960 + cl*30 + wc]
  __shared__ float wtb[28 * 72];        // [p*72 + gp*36 + ns*9 + k1*3+k2]
  __shared__ float ob[64 * 57];         // [(cl*2+ns1)*57 + p*2+ns2]

  int t = threadIdx.x;

  // fill xr: 288 rows (kk,cl) x 30 cols; batched register loads (chunks of 12)
  {
    int wc = t & 31;
    int r0 = t >> 5;                    // 0..7
    int wr = wbase + wc - 1;
    bool wok = (wc < 30) & (wr >= 0) & (wr < 56);
    const long xb0 = ((long)b * 256 + cbase) * 3136;
#pragma unroll
    for (int ch_ = 0; ch_ < 3; ++ch_) {
      float vals[12];
#pragma unroll
      for (int i = 0; i < 12; ++i) {
        int row = r0 + (ch_ * 12 + i) * 8;
        int kk = row >> 5, cl = row & 31;
        int k2 = kk / 3, k1 = kk - 3 * k2;
        int gr = (k2 * 56 + h) / 3 + k1 - 1;
        float v = 0.f;
        if (wok && gr >= 0 && gr < 56)
          v = x[xb0 + (long)cl * 3136 + gr * 56 + wr];
        vals[i] = v;
      }
#pragma unroll
      for (int i = 0; i < 12; ++i) {
        int row = r0 + (ch_ * 12 + i) * 8;
        if (wc < 30) xr[(row >> 5) * 960 + (row & 31) * 30 + wc] = (_Float16)vals[i];
      }
    }
  }
  // wt -> wtb (fp32 in LDS), unrolled
  {
    long m0 = ((long)(b * 56 + h)) * 56 + wbase;
    float vals[8];
#pragma unroll
    for (int i = 0; i < 8; ++i) {
      int idx = t + i * 256;
      if (idx < 2016) {
        int p = idx / 72, rem = idx - p * 72;
        vals[i] = (float)wt[(m0 + p) * 576 + cq * 72 + rem];
      }
    }
#pragma unroll
    for (int i = 0; i < 8; ++i) {
      int idx = t + i * 256;
      if (idx < 2016) wtb[idx] = vals[i];
    }
  }
  __syncthreads();

  {
    int cl = (t & 127) >> 2;
    int ns = t & 3;
    int ns1 = ns >> 1, ns2 = ns & 1;
    int psel = t >> 7;
    int gp = cl >> 4;
    int a2k[3];
#pragma unroll
    for (int k2 = 0; k2 < 3; ++k2)
      a2k[k2] = k2 * 2880 + cl * 30 + (k2 * 56 + h) % 3;
    int wtbase = gp * 36 + ns * 9;
    int obbase = (cl * 2 + ns1) * 57 + ns2;
#pragma unroll
    for (int it = 0; it < 14; ++it) {
      int p = it * 2 + psel;
      float accv = 0.f;
      int wpb = p * 72 + wtbase;
#pragma unroll
      for (int k1 = 0; k1 < 3; ++k1)
#pragma unroll
        for (int k2 = 0; k2 < 3; ++k2)
          accv += (float)xr[a2k[k2] + k1 * 960 + p] * wtb[wpb + k1 * 3 + k2];
      ob[obbase + p * 2] = accv;
    }
  }
  __syncthreads();

  // writeout: 64 rows x 56 cols; 4 rows/iter, unrolled
  {
    int wo = t & 63;
    int r0 = t >> 6;                    // 0..3
    const long obase = (((long)b * 256 + cbase) * 112 + 2 * h) * 112 + wh * 56;
#pragma unroll
    for (int i = 0; i < 16; ++i) {
      int row = r0 + i * 4;
      if (wo < 56) {
        int cli = row >> 1, n1 = row & 1;
        out[obase + cli * 12544 + n1 * 112 + wo] = ob[row * 57 + wo];
      }
    }
  }
}

extern "C" void kernel_launch(void* const* d_in, const int* in_sizes, int n_in,
                              void* d_out, int out_size, void* d_ws, size_t ws_size,
                              hipStream_t stream) {
  const float* x = (const float*)d_in[0];
  const float* w1 = (const float*)d_in[1];
  const float* gamma = (const float*)d_in[2];
  const float* beta = (const float*)d_in[3];
  const float* mean = (const float*)d_in[4];
  const float* var = (const float*)d_in[5];
  const float* w2 = (const float*)d_in[6];
  const float* b2 = (const float*)d_in[7];
  const float* w3 = (const float*)d_in[8];
  const float* b3 = (const float*)d_in[9];
  float* out = (float*)d_out;

  // workspace layout (bytes):
  //   weights hi/lo:   [0, 884736)
  //   wtg fp16:        [884736, 15335424)
  //   descH bf16:      [15335424, 68321280)
  //   descL bf16:      [68321280, 121307136)
  //   pacc fp32:       [121307136, 150208512)   (split-K partials)
  unsigned short* w1h = (unsigned short*)d_ws;
  unsigned short* w1l = w1h + 202752;
  unsigned short* w2h = w1l + 202752;
  unsigned short* w2l = w2h + 9216;
  unsigned short* w3h = w2l + 9216;
  unsigned short* w3l = w3h + 9216;
  _Float16* wtg = (_Float16*)((char*)d_ws + 884736);
  unsigned short* descH = (unsigned short*)((char*)d_ws + 15335424);
  unsigned short* descL = descH + 26492928;
  float* pacc = (float*)((char*)d_ws + 121307136);
  int uselo = (ws_size >= (size_t)121307136) ? 1 : 0;
  int splitk = (ws_size >= (size_t)150208512) ? 1 : 0;

  hipLaunchKernelGGL(kW, dim3(864), dim3(256), 0, stream,
                     w1, w2, w3, w1h, w1l, w2h, w2l, w3h, w3l);
  hipLaunchKernelGGL(kDesc, dim3(3584), dim3(320), 0, stream, x, descH, descL, uselo);
  if (splitk) {
    hipLaunchKernelGGL(kGemm1, dim3(1176), dim3(256), 0, stream,
                       descH, descL, w1h, w1l, pacc, uselo);
    hipLaunchKernelGGL(kGemm2, dim3(196), dim3(256), 0, stream,
                       pacc, w2h, w2l, w3h, w3l,
                       gamma, beta, mean, var, b2, b3, wtg);
  } else {
    hipLaunchKernelGGL(kGemmMono, dim3(196), dim3(256), 0, stream,
                       descH, descL, w1h, w1l, w2h, w2l, w3h, w3l,
                       gamma, beta, mean, var, b2, b3, wtg, uselo);
  }
  hipLaunchKernelGGL(kApply, dim3(3584), dim3(256), 0, stream, x, wtg, out);
}

// Round 5
// 217.429 us; speedup vs baseline: 1.9666x; 1.4897x over previous
//
#include <hip/hip_runtime.h>

typedef __attribute__((ext_vector_type(8))) _Float16 half8;
typedef __attribute__((ext_vector_type(4))) float floatx4;

// async global->LDS DMA, 16B per lane; lds must be wave-uniform base (+lane*16 implicit)
__device__ inline void gld16(const _Float16* g, _Float16* lds) {
  __builtin_amdgcn_global_load_lds(
      (const __attribute__((address_space(1))) unsigned int*)g,
      (__attribute__((address_space(3))) unsigned int*)lds, 16, 0, 0);
}

// ---------------- kW: fp32 -> fp16 weight planes ----------------
__global__ __launch_bounds__(256) void kW(const float* __restrict__ w1,
                                          const float* __restrict__ w2,
                                          const float* __restrict__ w3,
                                          _Float16* __restrict__ w1f,
                                          _Float16* __restrict__ w2f,
                                          _Float16* __restrict__ w3f) {
  int i = blockIdx.x * 256 + threadIdx.x;
  if (i < 202752) w1f[i] = (_Float16)w1[i];
  else if (i < 211968) w2f[i - 202752] = (_Float16)w2[i - 202752];
  else if (i < 221184) w3f[i - 211968] = (_Float16)w3[i - 211968];
}

// ---------------- kDesc: scrambled-unfold descriptors -> desc [12544, 2112] fp16 ----
// tap(k1,k2) at (h',w') = x[row=(k2*56+h')/3+k1-1, col=w'+(k2*56+h')%3-1], zero-pad.
__global__ __launch_bounds__(320) void kDesc(const float* __restrict__ x,
                                             _Float16* __restrict__ descF) {
  int bid = blockIdx.x;
  int g = bid & 15;
  int h = (bid >> 4) % 56;
  int b = bid / 896;
  __shared__ float xb[144 * 58];        // [(kk*16+ch)*58 + wc], kk=k2*3+k1
  __shared__ int tOff[4][132];
  __shared__ int tDg[132];

  int t = threadIdx.x;
  if (t < 132) {
    int dl = t;
    int o0, o1, o2, o3, dg;
    if (dl < 36) {                       // x1: max over 4 sub-channels
      int a3 = dl / 9, rem = dl % 9, k1 = rem / 3, k2 = rem % 3;
      int j2k = (k2 * 56 + h) % 3;
      int base = (k2 * 3 + k1) * 16;
      o0 = (base + a3) * 58 + j2k;
      o1 = (base + 4 + a3) * 58 + j2k;
      o2 = (base + 8 + a3) * 58 + j2k;
      o3 = (base + 12 + a3) * 58 + j2k;
      dg = g * 36 + dl;
    } else if (dl < 84) {                // x2: max over k1
      int u = dl - 36, gc = u / 3, k2 = u % 3;
      int j2k = (k2 * 56 + h) % 3;
      o0 = ((k2 * 3 + 0) * 16 + gc) * 58 + j2k;
      o1 = ((k2 * 3 + 1) * 16 + gc) * 58 + j2k;
      o2 = ((k2 * 3 + 2) * 16 + gc) * 58 + j2k;
      o3 = o0;
      dg = 576 + g * 48 + u;
    } else {                             // x3: max over k2
      int u = dl - 84, gc = u / 3, k1 = u % 3;
      o0 = ((0 * 3 + k1) * 16 + gc) * 58 + ((0 * 56 + h) % 3);
      o1 = ((1 * 3 + k1) * 16 + gc) * 58 + ((1 * 56 + h) % 3);
      o2 = ((2 * 3 + k1) * 16 + gc) * 58 + ((2 * 56 + h) % 3);
      o3 = o0;
      dg = 1344 + g * 48 + u;
    }
    tOff[0][dl] = o0; tOff[1][dl] = o1; tOff[2][dl] = o2; tOff[3][dl] = o3;
    tDg[dl] = dg;
  }

  // fill xb: 144 rows x 58 cols, batched loads for MLP
  {
    int wc = t & 63;
    int r0 = t >> 6;                     // 0..4
    int wr = wc - 1;
    bool wok = (wc < 58) & (wr >= 0) & (wr < 56);
    const long xb0 = ((long)b * 256 + g * 16) * 3136;
#pragma unroll
    for (int ch_ = 0; ch_ < 3; ++ch_) {
      const int nI = (ch_ < 2) ? 10 : 9;
      float vals[10];
#pragma unroll
      for (int i = 0; i < nI; ++i) {
        int row = r0 + (ch_ * 10 + i) * 5;
        int kk = row >> 4, ch = row & 15;
        int k2 = kk / 3, k1 = kk - 3 * k2;
        int gr = (k2 * 56 + h) / 3 + k1 - 1;
        float v = 0.f;
        if (wok && row < 144 && gr >= 0 && gr < 56)
          v = x[xb0 + ch * 3136 + (long)gr * 56 + wr];
        vals[i] = v;
      }
#pragma unroll
      for (int i = 0; i < nI; ++i) {
        int row = r0 + (ch_ * 10 + i) * 5;
        if (row < 144 && wc < 58) xb[row * 58 + wc] = vals[i];
      }
    }
  }
  __syncthreads();

  if (t < 264) {
    int p0 = (t >= 132) ? 1 : 0;
    int dl = t - p0 * 132;
    int o0 = tOff[0][dl], o1 = tOff[1][dl], o2 = tOff[2][dl], o3 = tOff[3][dl];
    long dbase = ((long)(b * 56 + h)) * 56 * 2112 + tDg[dl];
#pragma unroll
    for (int i = 0; i < 28; ++i) {
      int p = p0 + i * 2;
      float v = fmaxf(fmaxf(xb[o0 + p], xb[o1 + p]), fmaxf(xb[o2 + p], xb[o3 + p]));
      descF[dbase + (long)p * 2112] = (_Float16)v;
    }
  }
}

// ---------------- kGemm1: split-K partial GEMM, LDS-staged via global_load_lds ----------
// grid = 196 Mtiles x 6 K-chunks; 256 threads (4 waves); M=64, N=96, K-chunk=352, BK=32.
// LDS 20 KB, low VGPR -> 8 blocks/CU. fp16 partials out.
__global__ __launch_bounds__(256) void kGemm1(
    const _Float16* __restrict__ descF, const _Float16* __restrict__ w1f,
    _Float16* __restrict__ pacc) {
  __shared__ _Float16 Ab[2][64 * 32];   // [row*32 + c*8]
  __shared__ _Float16 Bb[2][96 * 32];   // [n*32 + c*8]
  const int t = threadIdx.x;
  const int wv = t >> 6, lane = t & 63, quad = lane >> 4, lr = lane & 15;
  const int mt = blockIdx.x / 6, ck = blockIdx.x % 6;
  const long mblk = (long)mt * 64;

  // staging maps (16B chunks): A chunk l=t -> row=l>>2, c=l&3; B same, plus l=256+t for t<128
  const long agbase = (mblk + (t >> 2)) * 2112 + ck * 352 + (t & 3) * 8;
  const long bg0 = (long)(t >> 2) * 2112 + ck * 352 + (t & 3) * 8;
  const long bg1 = (long)((256 + t) >> 2) * 2112 + ck * 352 + (t & 3) * 8;
  const int wslot = (t >> 6) * 512;     // wave-uniform LDS base (halves)

  floatx4 acc[6];
#pragma unroll
  for (int j = 0; j < 6; ++j) acc[j] = {0.f, 0.f, 0.f, 0.f};

  // prologue: stage tile 0 into buf 0
  gld16(descF + agbase, &Ab[0][wslot]);
  gld16(w1f + bg0, &Bb[0][wslot]);
  if (t < 128) gld16(w1f + bg1, &Bb[0][2048 + wslot]);

  int buf = 0;
  for (int kt = 0; kt < 11; ++kt) {
    __syncthreads();   // drains this wave's DMAs (incl. tile kt) and syncs buffer reuse
    if (kt < 10) {
      int off = (kt + 1) * 32;
      gld16(descF + agbase + off, &Ab[buf ^ 1][wslot]);
      gld16(w1f + bg0 + off, &Bb[buf ^ 1][wslot]);
      if (t < 128) gld16(w1f + bg1 + off, &Bb[buf ^ 1][2048 + wslot]);
    }
    half8 af = *(const half8*)(&Ab[buf][(wv * 16 + lr) * 32 + quad * 8]);
#pragma unroll
    for (int j = 0; j < 6; ++j) {
      half8 bf = *(const half8*)(&Bb[buf][(j * 16 + lr) * 32 + quad * 8]);
      acc[j] = __builtin_amdgcn_mfma_f32_16x16x32_f16(af, bf, acc[j], 0, 0, 0);
    }
    buf ^= 1;
  }

  _Float16* pp = pacc + (long)(ck * 196 + mt) * 6144;
#pragma unroll
  for (int j = 0; j < 6; ++j)
#pragma unroll
    for (int r = 0; r < 4; ++r)
      pp[(wv * 16 + quad * 4 + r) * 96 + j * 16 + lr] = (_Float16)acc[j][r];
}

// ---------------- kGemm2: sum partials -> BN/ReLU -> GEMM2 (w2,w3) -> softmax -> wt fp16 ----
// 196 blocks x 256 threads
__global__ __launch_bounds__(256) void kGemm2(
    const _Float16* __restrict__ pacc,
    const _Float16* __restrict__ w2f, const _Float16* __restrict__ w3f,
    const float* __restrict__ gamma, const float* __restrict__ beta,
    const float* __restrict__ mean, const float* __restrict__ var,
    const float* __restrict__ b2, const float* __restrict__ b3,
    _Float16* __restrict__ wtg) {
  __shared__ __align__(16) char smem[49152];
  float* ysum = (float*)smem;                              // [0, 24576): 6144 f32
  _Float16* ytF = (_Float16*)(smem + 24576);               // [24576, 37888): 64*104 fp16
  float* wal = (float*)smem;                               // phase3: 64*96 f32
  float* wbl = (float*)(smem + 24576);                     // phase3 (after ytF dead)
  __shared__ float invv[96], biasv[96];

  const int t = threadIdx.x;
  const int wv = t >> 6, lane = t & 63, quad = lane >> 4, lr = lane & 15;
  const int mt = blockIdx.x;
  const long mblk = (long)mt * 64;

  if (t < 96) {
    float iv = gamma[t] * rsqrtf(var[t] + 1e-5f);
    invv[t] = iv; biasv[t] = beta[t] - mean[t] * iv;
  }

  // coalesced fp16 partial reduction: ysum[idx] = sum_ck pacc[ck][mt][idx]
  {
    const _Float16* pb = pacc + (long)mt * 6144;
#pragma unroll
    for (int i = 0; i < 24; ++i) {
      int idx = t + i * 256;
      float s = 0.f;
#pragma unroll
      for (int ckk = 0; ckk < 6; ++ckk)
        s += (float)pb[(long)ckk * 196 * 6144 + idx];
      ysum[idx] = s;
    }
  }
  __syncthreads();

  // BN + ReLU -> ytF fp16 [64][104]
#pragma unroll
  for (int i = 0; i < 24; ++i) {
    int idx = t + i * 256;
    int m = idx / 96, n = idx - m * 96;
    float y = fmaxf(ysum[idx] * invv[n] + biasv[n], 0.f);
    ytF[m * 104 + n] = (_Float16)y;
  }
  __syncthreads();

  floatx4 acc2a[6], acc2b[6];
#pragma unroll
  for (int j = 0; j < 6; ++j) { acc2a[j] = {0.f,0.f,0.f,0.f}; acc2b[j] = {0.f,0.f,0.f,0.f}; }
#pragma unroll
  for (int ks = 0; ks < 3; ++ks) {
    half8 af = *(const half8*)(ytF + (wv * 16 + lr) * 104 + ks * 32 + quad * 8);
#pragma unroll
    for (int j = 0; j < 6; ++j) {
      int wo = (j * 16 + lr) * 96 + ks * 32 + quad * 8;
      half8 b2v = *(const half8*)(w2f + wo);
      half8 b3v = *(const half8*)(w3f + wo);
      acc2a[j] = __builtin_amdgcn_mfma_f32_16x16x32_f16(af, b2v, acc2a[j], 0, 0, 0);
      acc2b[j] = __builtin_amdgcn_mfma_f32_16x16x32_f16(af, b3v, acc2b[j], 0, 0, 0);
    }
  }
  __syncthreads();  // ysum/ytF dead; smem reused as wal/wbl

#pragma unroll
  for (int j = 0; j < 6; ++j) {
    int n = j * 16 + lr;
    float bb2 = b2[n], bb3 = b3[n];
#pragma unroll
    for (int r = 0; r < 4; ++r) {
      int m = wv * 16 + quad * 4 + r;
      wal[m * 96 + n] = acc2a[j][r] + bb2;
      wbl[m * 96 + n] = acc2b[j][r] + bb3;
    }
  }
  __syncthreads();

  // softmax over 9 logits la[k1]*lb[k2] per (m, g, ns1, ns2); /9 mean folded; fp16 out
  for (int it = 0; it < 16; ++it) {
    int u = t + it * 256;
    int m = u >> 6, rest = u & 63;
    int g = rest >> 2, ns = rest & 3;
    int ns1 = ns >> 1, ns2 = ns & 1;
    float la[3], lb[3];
#pragma unroll
    for (int k = 0; k < 3; ++k) {
      la[k] = wal[m * 96 + (g * 3 + k) * 2 + ns1];
      lb[k] = wbl[m * 96 + (g * 3 + k) * 2 + ns2];
    }
    float lg[9], mx = -1e30f;
#pragma unroll
    for (int k1 = 0; k1 < 3; ++k1)
#pragma unroll
      for (int k2 = 0; k2 < 3; ++k2) {
        float v = la[k1] * lb[k2];
        lg[k1 * 3 + k2] = v;
        mx = v > mx ? v : mx;
      }
    float s = 0.f;
#pragma unroll
    for (int k = 0; k < 9; ++k) { lg[k] = __expf(lg[k] - mx); s += lg[k]; }
    float sc = 1.f / (9.f * s);
    _Float16* dst = wtg + (mblk + m) * 576 + g * 36 + ns * 9;
#pragma unroll
    for (int k = 0; k < 9; ++k) dst[k] = (_Float16)(lg[k] * sc);
  }
}

// ---------------- kApply: x + wt -> out ----------
// block = (b, h', wh(2), cq(8)): 3584 blocks, 256 threads; 32 channels, 28 w-positions
__global__ __launch_bounds__(256) void kApply(const float* __restrict__ x,
                                              const _Float16* __restrict__ wt,
                                              float* __restrict__ out) {
  int bid = blockIdx.x;
  int cq = bid & 7;
  int wh = (bid >> 3) & 1;
  int h = (bid >> 4) % 56;
  int b = bid / 896;
  int wbase = wh * 28, cbase = cq * 32;

  __shared__ _Float16 xr[9 * 32 * 30];  // [kk*960 + cl*30 + wc]
  __shared__ float wtb[28 * 72];        // [p*72 + gp*36 + ns*9 + k1*3+k2]
  __shared__ float ob[64 * 57];         // [(cl*2+ns1)*57 + p*2+ns2]

  int t = threadIdx.x;

  // fill xr: 288 rows (kk,cl) x 30 cols; batched register loads
  {
    int wc = t & 31;
    int r0 = t >> 5;                    // 0..7
    int wr = wbase + wc - 1;
    bool wok = (wc < 30) & (wr >= 0) & (wr < 56);
    const long xb0 = ((long)b * 256 + cbase) * 3136;
#pragma unroll
    for (int ch_ = 0; ch_ < 3; ++ch_) {
      float vals[12];
#pragma unroll
      for (int i = 0; i < 12; ++i) {
        int row = r0 + (ch_ * 12 + i) * 8;
        int kk = row >> 5, cl = row & 31;
        int k2 = kk / 3, k1 = kk - 3 * k2;
        int gr = (k2 * 56 + h) / 3 + k1 - 1;
        float v = 0.f;
        if (wok && gr >= 0 && gr < 56)
          v = x[xb0 + (long)cl * 3136 + gr * 56 + wr];
        vals[i] = v;
      }
#pragma unroll
      for (int i = 0; i < 12; ++i) {
        int row = r0 + (ch_ * 12 + i) * 8;
        if (wc < 30) xr[(row >> 5) * 960 + (row & 31) * 30 + wc] = (_Float16)vals[i];
      }
    }
  }
  // wt -> wtb (fp32 in LDS)
  {
    long m0 = ((long)(b * 56 + h)) * 56 + wbase;
    float vals[8];
#pragma unroll
    for (int i = 0; i < 8; ++i) {
      int idx = t + i * 256;
      if (idx < 2016) {
        int p = idx / 72, rem = idx - p * 72;
        vals[i] = (float)wt[(m0 + p) * 576 + cq * 72 + rem];
      }
    }
#pragma unroll
    for (int i = 0; i < 8; ++i) {
      int idx = t + i * 256;
      if (idx < 2016) wtb[idx] = vals[i];
    }
  }
  __syncthreads();

  {
    int cl = (t & 127) >> 2;
    int ns = t & 3;
    int ns1 = ns >> 1, ns2 = ns & 1;
    int psel = t >> 7;
    int gp = cl >> 4;
    int a2k[3];
#pragma unroll
    for (int k2 = 0; k2 < 3; ++k2)
      a2k[k2] = k2 * 2880 + cl * 30 + (k2 * 56 + h) % 3;
    int wtbase = gp * 36 + ns * 9;
    int obbase = (cl * 2 + ns1) * 57 + ns2;
#pragma unroll
    for (int it = 0; it < 14; ++it) {
      int p = it * 2 + psel;
      float accv = 0.f;
      int wpb = p * 72 + wtbase;
#pragma unroll
      for (int k1 = 0; k1 < 3; ++k1)
#pragma unroll
        for (int k2 = 0; k2 < 3; ++k2)
          accv += (float)xr[a2k[k2] + k1 * 960 + p] * wtb[wpb + k1 * 3 + k2];
      ob[obbase + p * 2] = accv;
    }
  }
  __syncthreads();

  // writeout: 64 rows x 56 cols
  {
    int wo = t & 63;
    int r0 = t >> 6;                    // 0..3
    const long obase = (((long)b * 256 + cbase) * 112 + 2 * h) * 112 + wh * 56;
#pragma unroll
    for (int i = 0; i < 16; ++i) {
      int row = r0 + i * 4;
      if (wo < 56) {
        int cli = row >> 1, n1 = row & 1;
        out[obase + cli * 12544 + n1 * 112 + wo] = ob[row * 57 + wo];
      }
    }
  }
}

extern "C" void kernel_launch(void* const* d_in, const int* in_sizes, int n_in,
                              void* d_out, int out_size, void* d_ws, size_t ws_size,
                              hipStream_t stream) {
  const float* x = (const float*)d_in[0];
  const float* w1 = (const float*)d_in[1];
  const float* gamma = (const float*)d_in[2];
  const float* beta = (const float*)d_in[3];
  const float* mean = (const float*)d_in[4];
  const float* var = (const float*)d_in[5];
  const float* w2 = (const float*)d_in[6];
  const float* b2 = (const float*)d_in[7];
  const float* w3 = (const float*)d_in[8];
  const float* b3 = (const float*)d_in[9];
  float* out = (float*)d_out;

  // workspace layout (bytes), total ~82.3 MB:
  //   w1f fp16:   [0, 405504)
  //   w2f fp16:   [405504, 423936)
  //   w3f fp16:   [423936, 442368)
  //   wtg fp16:   [442368, 14893056)
  //   descF fp16: [14893056, 67878912)
  //   pacc fp16:  [67878912, 82329600)
  _Float16* w1f = (_Float16*)d_ws;
  _Float16* w2f = w1f + 202752;
  _Float16* w3f = w2f + 9216;
  _Float16* wtg = (_Float16*)((char*)d_ws + 442368);
  _Float16* descF = (_Float16*)((char*)d_ws + 14893056);
  _Float16* pacc = (_Float16*)((char*)d_ws + 67878912);

  hipLaunchKernelGGL(kW, dim3(864), dim3(256), 0, stream, w1, w2, w3, w1f, w2f, w3f);
  hipLaunchKernelGGL(kDesc, dim3(3584), dim3(320), 0, stream, x, descF);
  hipLaunchKernelGGL(kGemm1, dim3(1176), dim3(256), 0, stream, descF, w1f, pacc);
  hipLaunchKernelGGL(kGemm2, dim3(196), dim3(256), 0, stream,
                     pacc, w2f, w3f, gamma, beta, mean, var, b2, b3, wtg);
  hipLaunchKernelGGL(kApply, dim3(3584), dim3(256), 0, stream, x, wtg, out);
}